// Round 12
// baseline (289.502 us; speedup 1.0000x reference)
//
#include <hip/hip_runtime.h>

#define CH    256
#define MEM   684
#define POSN  128
#define NEGN  512
#define CLS   60
#define ROWS  41040
#define BATCHN 512

typedef unsigned int u32;
typedef unsigned short u16;
typedef unsigned long long u64;

typedef __attribute__((ext_vector_type(8))) short bf16x8;
typedef __attribute__((ext_vector_type(4))) float f32x4;

__device__ __forceinline__ float b2f(u16 u) { return __uint_as_float(((u32)u) << 16); }
__device__ __forceinline__ u16 f2b(float x) {
  u32 u = __float_as_uint(x);
  u32 r = ((u >> 16) & 1u) + 0x7FFFu;
  return (u16)((u + r) >> 16);
}
__device__ __forceinline__ u32 umin2(u32 a, u32 b) { return a < b ? a : b; }

// selection thresholds / caps
#define T1BASE 0.09375f   // hard-neg pre-filter (c > T1); bf16 bits 0x3DC0 exactly
#define T0BASE 0.03125f   // rand pre-filter (r < T0)
#define NBINC 512         // exact-value c-bins: bits - 0x3DC1 in [0, ~455]
#define BASEC 0x3DC1u
#define CAPC 3072         // legacy LDS c-list cap
#define CAPR 1536         // LDS r-list cap (E~1261, sd~35 -> 7.9 sigma)

// -------- async global->LDS staging (16B per lane) with fallback --------
#if defined(__has_builtin)
#if __has_builtin(__builtin_amdgcn_global_load_lds)
#define HAVE_GLL 1
#endif
#endif

__device__ __forceinline__ void stage16(const u16* g, u16* l) {
#ifdef HAVE_GLL
  __builtin_amdgcn_global_load_lds((const __attribute__((address_space(1))) void*)g,
                                   (__attribute__((address_space(3))) void*)l, 16, 0, 0);
#else
  *(uint4*)l = *(const uint4*)g;
#endif
}

// ---------------- K1: bank fp32 -> bf16 ----------------
__global__ __launch_bounds__(256) void k_convert(const float* __restrict__ bank,
                                                 u16* __restrict__ bankB) {
  size_t i = (size_t)(blockIdx.x * 256 + threadIdx.x) * 8;
  float4 a = *(const float4*)(bank + i);
  float4 b = *(const float4*)(bank + i + 4);
  uint4 o;
  o.x = (u32)f2b(a.x) | ((u32)f2b(a.y) << 16);
  o.y = (u32)f2b(a.z) | ((u32)f2b(a.w) << 16);
  o.z = (u32)f2b(b.x) | ((u32)f2b(b.y) << 16);
  o.w = (u32)f2b(b.z) | ((u32)f2b(b.w) << 16);
  *(uint4*)(bankB + i) = o;
}

// ---------------- K2: scatter f into bank, build fB ----------------
__global__ __launch_bounds__(256) void k_scatter(const float* __restrict__ f,
                                                 const int* __restrict__ enq,
                                                 u16* __restrict__ fB,
                                                 u16* __restrict__ bankB) {
  int n = blockIdx.x, t = threadIdx.x;
  u16 v = f2b(f[n * CH + t]);
  fB[n * CH + t] = v;
  int row = enq[n];
  bankB[(size_t)row * CH + t] = v;
}

// ---------------- K3: bf16 MFMA GEMM + fused c-histogram ----------------
// r11 lesson: only the c-HISTOGRAM needs the in-register c values (it
// summarizes all 41040/row). r-side and positives are gathered from Cb later
// by k_select. Epilogue emit = no-return atomicAdd only (r10 lesson: returned
// atomics serialize). No rnd read, no LDS staging, no copy-out.
__global__ __launch_bounds__(256) void k_gemm(const u16* __restrict__ fB,
                                              const u16* __restrict__ bankB,
                                              const int* __restrict__ label,
                                              u16* __restrict__ Cb,
                                              u32* __restrict__ histc_g,
                                              u32* __restrict__ ovf) {
  __shared__ __align__(16) u16 As[128 * 32];
  __shared__ __align__(16) u16 Bs[128 * 32];
  const int tid = threadIdx.x;
  const int wave = tid >> 6, lane = tid & 63;

  // bijective XCD swizzle: nwg=1284 = 8*160+4
  const u32 id = blockIdx.x;
  const u32 q = 160u, r4 = 4u;
  const u32 xcd = id & 7u, jj = id >> 3;
  const u32 wg = (xcd < r4 ? xcd * (q + 1u) : r4 * (q + 1u) + (xcd - r4) * q) + jj;
  const int bm = (int)(wg & 3u) * 128;
  const int bn = (int)(wg >> 2) * 128;

  const int wm = (wave & 1) * 64, wn = (wave >> 1) * 64;
  const int m_in = lane & 15;
  const int ks = (lane >> 4) * 8;

  f32x4 acc[4][4] = {};

  for (int k0 = 0; k0 < CH; k0 += 32) {
    __syncthreads();
#pragma unroll
    for (int i = 0; i < 2; i++) {
      int u = tid + 256 * i;
      int row = u >> 2;
      int kk = (u & 3) * 8;
      stage16(fB + (size_t)(bm + row) * CH + k0 + kk, As + u * 8);
      int rb = bn + row;
      if (rb >= ROWS) rb = bn;
      stage16(bankB + (size_t)rb * CH + k0 + kk, Bs + u * 8);
    }
    __syncthreads();

    bf16x8 af[4], bf[4];
#pragma unroll
    for (int t4 = 0; t4 < 4; t4++) {
      af[t4] = *(const bf16x8*)(As + (wm + t4 * 16 + m_in) * 32 + ks);
      bf[t4] = *(const bf16x8*)(Bs + (wn + t4 * 16 + m_in) * 32 + ks);
    }
    // swapped operands: D[n][m] so regs q span 4 consecutive N columns
#pragma unroll
    for (int mi = 0; mi < 4; mi++)
#pragma unroll
      for (int ni = 0; ni < 4; ni++)
        acc[mi][ni] = __builtin_amdgcn_mfma_f32_16x16x32_bf16(bf[ni], af[mi], acc[mi][ni], 0, 0, 0);
  }

  const int cc = lane & 15;        // M offset within 16
  const int rr = (lane >> 4) * 4;  // N offset within 16
#pragma unroll
  for (int mi = 0; mi < 4; mi++) {
    const int row = bm + wm + mi * 16 + cc;  // < 512
    const int labr = label[row];
#pragma unroll
    for (int ni = 0; ni < 4; ni++) {
      const int n0 = bn + wn + ni * 16 + rr;
      if (n0 < ROWS) {  // groups of 4 fully in/out (ROWS%4==0)
        u16 h0 = f2b(acc[mi][ni][0]), h1 = f2b(acc[mi][ni][1]);
        u16 h2 = f2b(acc[mi][ni][2]), h3 = f2b(acc[mi][ni][3]);
        u64 pk = (u64)h0 | ((u64)h1 << 16) | ((u64)h2 << 32) | ((u64)h3 << 48);
        *(u64*)(Cb + (size_t)row * ROWS + n0) = pk;

        // c-histogram (negatives only; positive bf16 is bit-monotonic)
        int j60 = n0 / 60;
        int rmod = n0 - j60 * 60;
        u16 hs[4] = {h0, h1, h2, h3};
#pragma unroll
        for (int qq = 0; qq < 4; qq++) {
          u16 hb = hs[qq];
          if (rmod != labr && hb > 0x3DC0u && hb < 0x8000u) {
            u32 bin = (u32)hb - BASEC;
            if (bin < NBINC) atomicAdd(&histc_g[((u32)row << 9) + bin], 1u);  // no-return
            else ovf[row] = 1;  // impossible for |dot|<=1.06; safety only
          }
          rmod++;
          if (rmod == 60) rmod = 0;
        }
      }
    }
  }
}

// ---------------- block helpers (1024 threads, wave=64) ----------------
__device__ __forceinline__ u32 wscan_incl(u32 v) {
  int lane = (int)(threadIdx.x & 63);
#pragma unroll
  for (int off = 1; off < 64; off <<= 1) {
    u32 t = __shfl_up(v, off, 64);
    if (lane >= off) v += t;
  }
  return v;
}

__device__ __forceinline__ u32 scan1024(u32 v, u32* tmp, int tid) {
  u32 inc = wscan_incl(v);
  int wid = tid >> 6;
  if ((tid & 63) == 63) tmp[wid] = inc;
  __syncthreads();
  if (tid < 64) {
    u32 t = (tid < 16) ? tmp[tid] : 0u;
    u32 ti = wscan_incl(t);
    if (tid < 16) tmp[tid] = ti - t;
  }
  __syncthreads();
  u32 r = inc + tmp[wid];
  __syncthreads();
  return r;
}

__device__ __forceinline__ float redsum1024(float v, float* tmp, int tid) {
#pragma unroll
  for (int off = 32; off > 0; off >>= 1) v += __shfl_xor(v, off, 64);
  int wid = tid >> 6;
  if ((tid & 63) == 0) tmp[wid] = v;
  __syncthreads();
  if (tid == 0) {
    float t = 0.f;
#pragma unroll
    for (int i = 0; i < 16; i++) t += tmp[i];
    tmp[0] = t;
  }
  __syncthreads();
  float r = tmp[0];
  __syncthreads();
  return r;
}

__device__ __forceinline__ int binof(float v, float lo, float scale) {
  int b = (int)((v - lo) * scale);
  return b < 0 ? 0 : (b > 2047 ? 2047 : b);
}

// ---------------- K4: per-row selection + loss terms ----------------
// FAST: c-side entirely from the exact-value histogram (F, boundary VALUE,
// cnt_gt, S_H, tie-correction need_c*exp(v_b) -- all exact since boundary-bin
// values are bit-identical). Phase A streams ONLY rrow (half of r5's load
// chain); c for surviving r-candidates (~520/row) gathered from L2/L3-hot Cb.
// Positives read directly from Cb (r5 style). LEGACY full scan kept verbatim
// (rolled loops -- spill lesson r2-r4) gated on ovf/counts; never taken here.
#define VITER 5
#define VTAIL 80
#define VTAILBASE 40960

__global__ __launch_bounds__(1024, 8) void k_select(const u16* __restrict__ Cb,
                                                    const float* __restrict__ rnd,
                                                    const int* __restrict__ label,
                                                    const u32* __restrict__ histc_g,
                                                    const u32* __restrict__ ovf,
                                                    float* __restrict__ partial) {
  const int n = blockIdx.x;
  const int tid = threadIdx.x;
  const u16* crow = Cb + (size_t)n * ROWS;
  const float* rrow = rnd + (size_t)n * ROWS;
  const int lab = label[n];

  __shared__ __align__(16) char smem[56448];
  u32* histc = (u32*)(smem);                // 2048 u32 (legacy + positives)
  u32* histr = (u32*)(smem + 8192);         // 2048 u32
  float* clist = (float*)(smem + 16384);    // 3072 f32 (legacy only)
  float* rl_rv = (float*)(smem + 28672);    // 1536 f32
  float* rl_cv = (float*)(smem + 34816);    // 1536 f32 (legacy only)
  u32* rl_mi = (u32*)(smem + 40960);        // 1536 u32
  u32* stmp = (u32*)(smem + 47104);         // 1024 u32 (fred aliases)
  float* fred = (float*)(smem + 47104);
  float* cb_c = (float*)(smem + 51200);     // 512 f32
  float* rb_r = (float*)(smem + 53248);     // 256 f32
  float* rb_c = (float*)(smem + 54272);     // 256 f32
  u32* rb_m = (u32*)(smem + 55296);         // 256 u32
  u32* ctl = (u32*)(smem + 56320);
  float* bc_f = (float*)(ctl + 8);

  const u32 ov = ovf[n];
  const int rv0 = (tid * 8) % 60;

  // ---- c-side: exact-value histogram scan (F + boundary prep) ----
  const u32* hrow = histc_g + ((u32)n << 9);
  u32 cbc = (tid < NBINC) ? hrow[tid] : 0u;
  u32 cinc = scan1024(cbc, stmp, tid);
  u32 cexc = cinc - cbc;
  if (tid == 1023) ctl[0] = cinc;
  __syncthreads();
  const u32 Fh = ctl[0];

  // ---- phase A-r: stream rrow ONLY -> LDS (rv, mi) list + histr ----
  for (int i = tid; i < 2048; i += 1024) histr[i] = 0;
  if (tid == 0) ctl[1] = 0;
  __syncthreads();
  const float sc_r = 2048.0f / T0BASE;
  {
    int rb = rv0;
#pragma unroll 1
    for (int it = 0; it < VITER; it++) {
      int m8 = (it * 1024 + tid) * 8;
      float4 ra = *(const float4*)(rrow + m8);
      float4 rb4 = *(const float4*)(rrow + m8 + 4);
      float rs[8] = {ra.x, ra.y, ra.z, ra.w, rb4.x, rb4.y, rb4.z, rb4.w};
      u32 mr = 0;
      int r = rb;
#pragma unroll
      for (int j = 0; j < 8; j++) {
        if (r != lab && rs[j] < T0BASE) mr |= (1u << j);
        r++;
        if (r == 60) r = 0;
      }
      u32 s2 = 0;
      if (mr) s2 = atomicAdd(&ctl[1], (u32)__popc(mr));
#pragma unroll
      for (int j = 0; j < 8; j++) {
        if (mr & (1u << j)) {
          if (s2 < CAPR) { rl_rv[s2] = rs[j]; rl_mi[s2] = (u32)(m8 + j); }
          atomicAdd(&histr[binof(rs[j], 0.0f, sc_r)], 1u);
          s2++;
        }
      }
      rb += 32;  // 8192 % 60
      if (rb >= 60) rb -= 60;
    }
    if (tid < VTAIL) {
      int m = VTAILBASE + tid;
      int r = 40 + tid;  // 40960 % 60 = 40
      if (r >= 60) r -= 60;
      float rv = rrow[m];
      if (r != lab && rv < T0BASE) {
        u32 s2 = atomicAdd(&ctl[1], 1u);
        if (s2 < CAPR) { rl_rv[s2] = rv; rl_mi[s2] = (u32)m; }
        atomicAdd(&histr[binof(rv, 0.0f, sc_r)], 1u);
      }
    }
  }
  __syncthreads();
  const u32 G = ctl[1];
  __syncthreads();

  const bool fast = (ov == 0u) && Fh >= NEGN && G >= NEGN && G <= CAPR;

  float S_H, S_R;
  if (fast) {
    if (tid == 0) { ctl[3] = 0; ctl[4] = 0; ctl[5] = 0; ctl[6] = 0; ctl[7] = 0; }
    __syncthreads();
    // c boundary from exact-value bins
    u32 tcpos = Fh - NEGN + 1;
    if (tid < NBINC && cexc < tcpos && tcpos <= cinc) {
      ctl[4] = (u32)tid;       // boundary bin
      ctl[5] = Fh - cinc;      // cnt strictly above boundary bin
    }
    __syncthreads();
    const u32 b_c = ctl[4], cnt_gt = ctl[5];
    const u32 need_c = NEGN - cnt_gt;
    float sH = 0.f;
    if (tid < NBINC && (u32)tid > b_c && cbc)
      sH = (float)cbc * expf(b2f((u16)(BASEC + (u32)tid)));
    float SHsum = redsum1024(sH, fred, tid);
    S_H = SHsum + (float)need_c * expf(b2f((u16)(BASEC + b_c)));

    // r boundary from histr
    u32 gsum = histr[tid * 2] + histr[tid * 2 + 1];
    u32 ginc = scan1024(gsum, stmp, tid);
    u32 gexc = ginc - gsum;
    if (gexc < NEGN && NEGN <= ginc) {
      u32 run = gexc;
#pragma unroll
      for (int i = 0; i < 2; i++) {
        u32 h = histr[tid * 2 + i];
        if (run + h >= NEGN) { ctl[6] = (u32)(tid * 2 + i); ctl[7] = run; break; }
        run += h;
      }
    }
    __syncthreads();
    const u32 b_r = ctl[6], cnt_lt = ctl[7];
    const u32 need_r = NEGN - cnt_lt;

    // phase B-r: gather c from Cb for selected candidates (L2/L3-hot)
    float sR = 0.f;
    for (u32 i = tid; i < G; i += 1024) {
      float rv = rl_rv[i];
      u32 b = (u32)binof(rv, 0.0f, sc_r);
      if (b < b_r) sR += expf(b2f(crow[rl_mi[i]]));
      else if (b == b_r) {
        u32 id = atomicAdd(&ctl[3], 1u);
        if (id < 256) {
          rb_r[id] = rv;
          rb_c[id] = b2f(crow[rl_mi[i]]);
          rb_m[id] = rl_mi[i];
        }
      }
    }
    __syncthreads();
    float SRsum = redsum1024(sR, fred, tid);
    if (tid == 0) {
      // boundary bin: stable order = (rand value, index) ascending
      u32 Lr = umin2(ctl[3], 256u);
      for (u32 i = 1; i < Lr; i++) {
        float rv = rb_r[i]; u32 mm = rb_m[i]; float cv = rb_c[i];
        int j = (int)i - 1;
        while (j >= 0 && (rb_r[j] > rv || (rb_r[j] == rv && rb_m[j] > mm))) {
          rb_r[j + 1] = rb_r[j]; rb_m[j + 1] = rb_m[j]; rb_c[j + 1] = rb_c[j];
          j--;
        }
        rb_r[j + 1] = rv; rb_m[j + 1] = mm; rb_c[j + 1] = cv;
      }
      float addR = 0.f;
      u32 kr = umin2(need_r, Lr);
      for (u32 i = 0; i < kr; i++) addR += expf(rb_c[i]);
      bc_f[1] = addR;
    }
    __syncthreads();
    S_R = SRsum + bc_f[1];
    __syncthreads();
  } else {
    // ---- LEGACY: r5 full scan with retry (rolled loops; spill lesson r2-r4) ----
    float T1 = T1BASE, T0 = T0BASE;
    u32 F = 0, Gl = 0;
    float sc_c, sc_rl;
    for (int attempt = 0;; attempt++) {
      for (int i = tid; i < 2048; i += 1024) { histc[i] = 0; histr[i] = 0; }
      if (tid == 0) { ctl[0] = 0; ctl[1] = 0; }
      __syncthreads();
      sc_c = 2048.0f / (1.0625f - T1);
      sc_rl = 2048.0f / T0;
      int rb = rv0;
#pragma unroll 1
      for (int it = 0; it < VITER; it++) {
        int m8 = (it * 1024 + tid) * 8;
        uint4 cr = *(const uint4*)(crow + m8);
        float4 ra = *(const float4*)(rrow + m8);
        float4 rb4 = *(const float4*)(rrow + m8 + 4);
        u32 cw[4] = {cr.x, cr.y, cr.z, cr.w};
        float rs[8] = {ra.x, ra.y, ra.z, ra.w, rb4.x, rb4.y, rb4.z, rb4.w};
        u32 mc = 0, mr = 0;
        int r = rb;
#pragma unroll
        for (int j = 0; j < 8; j++) {
          bool isneg = (r != lab);
          float c = b2f((u16)(cw[j >> 1] >> ((j & 1) * 16)));
          if (isneg && c > T1) mc |= (1u << j);
          if (isneg && rs[j] < T0) mr |= (1u << j);
          r++;
          if (r == 60) r = 0;
        }
        u32 s1 = 0, s2 = 0;
        if (mc) s1 = atomicAdd(&ctl[0], (u32)__popc(mc));
        if (mr) s2 = atomicAdd(&ctl[1], (u32)__popc(mr));
#pragma unroll
        for (int j = 0; j < 8; j++) {
          if (mc & (1u << j)) {
            float c = b2f((u16)(cw[j >> 1] >> ((j & 1) * 16)));
            if (s1 < CAPC) clist[s1] = c;
            atomicAdd(&histc[binof(c, T1, sc_c)], 1u);
            s1++;
          }
          if (mr & (1u << j)) {
            float c = b2f((u16)(cw[j >> 1] >> ((j & 1) * 16)));
            if (s2 < CAPR) { rl_rv[s2] = rs[j]; rl_cv[s2] = c; rl_mi[s2] = (u32)(m8 + j); }
            atomicAdd(&histr[binof(rs[j], 0.0f, sc_rl)], 1u);
            s2++;
          }
        }
        rb += 32;
        if (rb >= 60) rb -= 60;
      }
      if (tid < VTAIL) {
        int m = VTAILBASE + tid;
        int r = 40 + tid;
        if (r >= 60) r -= 60;
        bool isneg = (r != lab);
        float c = b2f(crow[m]);
        if (isneg && c > T1) {
          u32 s1 = atomicAdd(&ctl[0], 1u);
          if (s1 < CAPC) clist[s1] = c;
          atomicAdd(&histc[binof(c, T1, sc_c)], 1u);
        }
        float rv = rrow[m];
        if (isneg && rv < T0) {
          u32 s2 = atomicAdd(&ctl[1], 1u);
          if (s2 < CAPR) { rl_rv[s2] = rv; rl_cv[s2] = c; rl_mi[s2] = (u32)m; }
          atomicAdd(&histr[binof(rv, 0.0f, sc_rl)], 1u);
        }
      }
      __syncthreads();
      F = ctl[0];
      Gl = ctl[1];
      __syncthreads();
      if (F >= NEGN && Gl >= NEGN) break;
      if (F < NEGN) T1 = -1.1f;
      if (Gl < NEGN) T0 = 1.1f;
    }
    const bool listc_ok = (F <= CAPC);
    const bool listr_ok = (Gl <= CAPR);

    if (tid == 0) { ctl[2] = 0; ctl[3] = 0; ctl[4] = 0; ctl[5] = 0; ctl[6] = 0; ctl[7] = 0; }
    u32 fsum = histc[tid * 2] + histc[tid * 2 + 1];
    u32 finc = scan1024(fsum, stmp, tid);
    u32 fexc = finc - fsum;
    u32 tcpos = F - NEGN + 1;
    if (fexc < tcpos && tcpos <= finc) {
      u32 run = fexc;
#pragma unroll
      for (int i = 0; i < 2; i++) {
        u32 h = histc[tid * 2 + i];
        if (run + h >= tcpos) { ctl[4] = (u32)(tid * 2 + i); ctl[5] = F - (run + h); break; }
        run += h;
      }
    }
    u32 gsum = histr[tid * 2] + histr[tid * 2 + 1];
    u32 ginc = scan1024(gsum, stmp, tid);
    u32 gexc = ginc - gsum;
    if (gexc < NEGN && NEGN <= ginc) {
      u32 run = gexc;
#pragma unroll
      for (int i = 0; i < 2; i++) {
        u32 h = histr[tid * 2 + i];
        if (run + h >= NEGN) { ctl[6] = (u32)(tid * 2 + i); ctl[7] = run; break; }
        run += h;
      }
    }
    __syncthreads();
    const u32 b_c = ctl[4], cnt_gt = ctl[5];
    const u32 b_r = ctl[6], cnt_lt = ctl[7];
    const u32 need_c = NEGN - cnt_gt;
    const u32 need_r = NEGN - cnt_lt;

    float sH = 0.f, sR = 0.f;
    if (listc_ok) {
      for (u32 i = tid; i < F; i += 1024) {
        float c = clist[i];
        u32 b = (u32)binof(c, T1, sc_c);
        if (b > b_c) sH += expf(c);
        else if (b == b_c) {
          u32 id = atomicAdd(&ctl[2], 1u);
          if (id < 512) cb_c[id] = c;
        }
      }
    }
    if (listr_ok) {
      for (u32 i = tid; i < Gl; i += 1024) {
        float rv = rl_rv[i];
        u32 b = (u32)binof(rv, 0.0f, sc_rl);
        if (b < b_r) sR += expf(rl_cv[i]);
        else if (b == b_r) {
          u32 id = atomicAdd(&ctl[3], 1u);
          if (id < 256) { rb_r[id] = rv; rb_c[id] = rl_cv[i]; rb_m[id] = rl_mi[i]; }
        }
      }
    }
    if (!listc_ok || !listr_ok) {
      for (int m = tid; m < ROWS; m += 1024) {
        int r = m % 60;
        if (r == lab) continue;
        float c = b2f(crow[m]);
        if (!listc_ok && c > T1) {
          u32 b = (u32)binof(c, T1, sc_c);
          if (b > b_c) sH += expf(c);
          else if (b == b_c) {
            u32 id = atomicAdd(&ctl[2], 1u);
            if (id < 512) cb_c[id] = c;
          }
        }
        if (!listr_ok) {
          float rv = rrow[m];
          if (rv < T0) {
            u32 b = (u32)binof(rv, 0.0f, sc_rl);
            if (b < b_r) sR += expf(c);
            else if (b == b_r) {
              u32 id = atomicAdd(&ctl[3], 1u);
              if (id < 256) { rb_r[id] = rv; rb_c[id] = c; rb_m[id] = (u32)m; }
            }
          }
        }
      }
    }
    __syncthreads();
    float SHsum = redsum1024(sH, fred, tid);
    float SRsum = redsum1024(sR, fred, tid);

    if (tid == 0) {
      float addH = 0.f;
      u32 Lc = umin2(ctl[2], 512u);
      u32 kc = umin2(need_c, Lc);
      for (u32 k = 0; k < kc; k++) {
        int best = 0;
        float bv = -3.0e38f;
        for (u32 i = 0; i < Lc; i++)
          if (cb_c[i] > bv) { bv = cb_c[i]; best = (int)i; }
        cb_c[best] = -3.0e38f;
        addH += expf(bv);
      }
      u32 Lr = umin2(ctl[3], 256u);
      for (u32 i = 1; i < Lr; i++) {
        float rv = rb_r[i]; u32 mm = rb_m[i]; float cv = rb_c[i];
        int j = (int)i - 1;
        while (j >= 0 && (rb_r[j] > rv || (rb_r[j] == rv && rb_m[j] > mm))) {
          rb_r[j + 1] = rb_r[j]; rb_m[j + 1] = rb_m[j]; rb_c[j + 1] = rb_c[j];
          j--;
        }
        rb_r[j + 1] = rv; rb_m[j + 1] = mm; rb_c[j + 1] = cv;
      }
      float addR = 0.f;
      u32 kr = umin2(need_r, Lr);
      for (u32 i = 0; i < kr; i++) addR += expf(rb_c[i]);
      bc_f[0] = addH;
      bc_f[1] = addR;
    }
    __syncthreads();
    S_H = SHsum + bc_f[0];
    S_R = SRsum + bc_f[1];
    __syncthreads();
  }

  // ---- positives: 128 smallest of 684 via histogram rank-selection ----
  // read directly from Cb (row is L2/L3-hot)
  float pval = 0.f;
  int pbin = 0;
  const bool hasp = tid < MEM;
  const float PLO = -1.03125f;
  const float PSC = 2048.0f / 2.09375f;
  if (hasp) {
    pval = b2f(crow[lab + CLS * tid]);
    pbin = binof(pval, PLO, PSC);
  }
  for (int i = tid; i < 2048; i += 1024) histc[i] = 0;
  if (tid == 0) { ctl[2] = 0; ctl[4] = 0; ctl[5] = 0; }
  __syncthreads();
  if (hasp) atomicAdd(&histc[pbin], 1u);
  __syncthreads();
  u32 hsum = histc[tid * 2] + histc[tid * 2 + 1];
  u32 hinc = scan1024(hsum, stmp, tid);
  u32 hexc = hinc - hsum;
  if (hexc < POSN && POSN <= hinc) {
    u32 run = hexc;
#pragma unroll
    for (int i = 0; i < 2; i++) {
      u32 h = histc[tid * 2 + i];
      if (run + h >= POSN) { ctl[4] = (u32)(tid * 2 + i); ctl[5] = run; break; }
      run += h;
    }
  }
  __syncthreads();
  const u32 b_p = ctl[4], cnt_below = ctl[5];
  const u32 need_p = POSN - cnt_below;
  if (hasp && (u32)pbin == b_p) {
    u32 id = atomicAdd(&ctl[2], 1u);
    if (id < 512) cb_c[id] = pval;
  }
  float term = 0.f;
  if (hasp && (u32)pbin < b_p) {
    float e = expf(pval);
    term = (pval - logf(e + S_H)) + (pval - logf(e + S_R));
  }
  __syncthreads();
  if (tid == 0) {
    u32 L = umin2(ctl[2], 512u);
    u32 kp = umin2(need_p, L);
    float add = 0.f;
    for (u32 k = 0; k < kp; k++) {
      int best = 0;
      float bv = 3.0e38f;
      for (u32 i = 0; i < L; i++)
        if (cb_c[i] < bv) { bv = cb_c[i]; best = (int)i; }
      cb_c[best] = 3.0e38f;
      float e = expf(bv);
      add += (bv - logf(e + S_H)) + (bv - logf(e + S_R));
    }
    bc_f[0] = add;
  }
  __syncthreads();
  float tot = redsum1024(term, fred, tid);
  if (tid == 0) partial[n] = tot + bc_f[0];
}

// ---------------- K5: final reduce ----------------
__global__ __launch_bounds__(256) void k_final(const float* __restrict__ partial,
                                               float* __restrict__ out) {
  __shared__ float fred[256];
  int tid = threadIdx.x;
  float v = partial[tid] + partial[tid + 256];
  fred[tid] = v;
  __syncthreads();
  for (int off = 128; off > 0; off >>= 1) {
    if (tid < off) fred[tid] += fred[tid + off];
    __syncthreads();
  }
  if (tid == 0) out[0] = -fred[0] / (float)(BATCHN * 2 * POSN);
}

extern "C" void kernel_launch(void* const* d_in, const int* in_sizes, int n_in,
                              void* d_out, int out_size, void* d_ws, size_t ws_size,
                              hipStream_t stream) {
  const float* f = (const float*)d_in[0];
  const int* label = (const int*)d_in[1];
  const int* enq = (const int*)d_in[2];
  const float* bank = (const float*)d_in[3];
  const float* rnd = (const float*)d_in[5];
  float* out = (float*)d_out;

  // workspace layout (~64.4 MB total)
  char* ws = (char*)d_ws;
  u16* bankB = (u16*)ws;                          // 21,012,480
  u16* fB = (u16*)(ws + 21012480);                //    262,144
  u16* Cb = (u16*)(ws + 21274624);                // 42,024,960
  float* partial = (float*)(ws + 63299584);       //      2,048
  u32* histc_g = (u32*)(ws + 63301632);           //  1,048,576 (512 rows * 512 bins)
  u32* ovf = (u32*)(ws + 64350208);               //      2,048

  // zero histc_g + ovf in one contiguous memset
  hipMemsetAsync(histc_g, 0, 1050624, stream);

  k_convert<<<dim3(5130), dim3(256), 0, stream>>>(bank, bankB);
  k_scatter<<<dim3(BATCHN), dim3(256), 0, stream>>>(f, enq, fB, bankB);
  k_gemm<<<dim3(1284), dim3(256), 0, stream>>>(fB, bankB, label, Cb, histc_g, ovf);
  k_select<<<dim3(BATCHN), dim3(1024), 0, stream>>>(Cb, rnd, label, histc_g, ovf, partial);
  k_final<<<dim3(1), dim3(256), 0, stream>>>(partial, out);
}

// Round 13
// 213.486 us; speedup vs baseline: 1.3561x; 1.3561x over previous
//
#include <hip/hip_runtime.h>

#define CH    256
#define MEM   684
#define POSN  128
#define NEGN  512
#define CLS   60
#define ROWS  41040
#define BATCHN 512

typedef unsigned int u32;
typedef unsigned short u16;
typedef unsigned long long u64;

typedef __attribute__((ext_vector_type(8))) short bf16x8;
typedef __attribute__((ext_vector_type(4))) float f32x4;

__device__ __forceinline__ float b2f(u16 u) { return __uint_as_float(((u32)u) << 16); }
__device__ __forceinline__ u16 f2b(float x) {
  u32 u = __float_as_uint(x);
  u32 r = ((u >> 16) & 1u) + 0x7FFFu;
  return (u16)((u + r) >> 16);
}
__device__ __forceinline__ u32 umin2(u32 a, u32 b) { return a < b ? a : b; }

// selection thresholds / caps
#define T1BASE 0.09375f   // hard-neg pre-filter (c > T1); bf16 bits 0x3DC0 exactly
#define T0BASE 0.03125f   // rand pre-filter (r < T0)
#define NBINC 512         // exact-value c-bins: bits - 0x3DC1 (max ~448 for |c|<=1.06)
#define BASEC 0x3DC1u
#define CAPC 3072         // legacy LDS c-list cap
#define CAPR 1536         // LDS r-list cap (E~1261, sd~35 -> 7.9 sigma)

// -------- async global->LDS staging (16B per lane) with fallback --------
#if defined(__has_builtin)
#if __has_builtin(__builtin_amdgcn_global_load_lds)
#define HAVE_GLL 1
#endif
#endif

__device__ __forceinline__ void stage16(const u16* g, u16* l) {
#ifdef HAVE_GLL
  __builtin_amdgcn_global_load_lds((const __attribute__((address_space(1))) void*)g,
                                   (__attribute__((address_space(3))) void*)l, 16, 0, 0);
#else
  *(uint4*)l = *(const uint4*)g;
#endif
}

// ---------------- K1: bank fp32 -> bf16 ----------------
__global__ __launch_bounds__(256) void k_convert(const float* __restrict__ bank,
                                                 u16* __restrict__ bankB) {
  size_t i = (size_t)(blockIdx.x * 256 + threadIdx.x) * 8;
  float4 a = *(const float4*)(bank + i);
  float4 b = *(const float4*)(bank + i + 4);
  uint4 o;
  o.x = (u32)f2b(a.x) | ((u32)f2b(a.y) << 16);
  o.y = (u32)f2b(a.z) | ((u32)f2b(a.w) << 16);
  o.z = (u32)f2b(b.x) | ((u32)f2b(b.y) << 16);
  o.w = (u32)f2b(b.z) | ((u32)f2b(b.w) << 16);
  *(uint4*)(bankB + i) = o;
}

// ---------------- K2: scatter f into bank, build fB ----------------
__global__ __launch_bounds__(256) void k_scatter(const float* __restrict__ f,
                                                 const int* __restrict__ enq,
                                                 u16* __restrict__ fB,
                                                 u16* __restrict__ bankB) {
  int n = blockIdx.x, t = threadIdx.x;
  u16 v = f2b(f[n * CH + t]);
  fB[n * CH + t] = v;
  int row = enq[n];
  bankB[(size_t)row * CH + t] = v;
}

// ---------------- K3: bf16 MFMA GEMM  Cb[512][41040] = fB * bankB^T ----------------
// PLAIN gemm (r10-r12 lesson: ANY fused global-atomic emit costs 55-400us --
// cross-XCD atomic line bouncing; the histogram now lives in k_select's LDS).
// XCD-bijective swizzle, operand-swapped MFMA -> packed 8B C-stores.
__global__ __launch_bounds__(256) void k_gemm(const u16* __restrict__ fB,
                                              const u16* __restrict__ bankB,
                                              u16* __restrict__ Cb) {
  __shared__ __align__(16) u16 As[128 * 32];
  __shared__ __align__(16) u16 Bs[128 * 32];
  const int tid = threadIdx.x;
  const int wave = tid >> 6, lane = tid & 63;

  // bijective XCD swizzle: nwg=1284 = 8*160+4
  const u32 id = blockIdx.x;
  const u32 q = 160u, r4 = 4u;
  const u32 xcd = id & 7u, jj = id >> 3;
  const u32 wg = (xcd < r4 ? xcd * (q + 1u) : r4 * (q + 1u) + (xcd - r4) * q) + jj;
  const int bm = (int)(wg & 3u) * 128;
  const int bn = (int)(wg >> 2) * 128;

  const int wm = (wave & 1) * 64, wn = (wave >> 1) * 64;
  const int m_in = lane & 15;
  const int ks = (lane >> 4) * 8;

  f32x4 acc[4][4] = {};

  for (int k0 = 0; k0 < CH; k0 += 32) {
    __syncthreads();
#pragma unroll
    for (int i = 0; i < 2; i++) {
      int u = tid + 256 * i;
      int row = u >> 2;
      int kk = (u & 3) * 8;
      stage16(fB + (size_t)(bm + row) * CH + k0 + kk, As + u * 8);
      int rb = bn + row;
      if (rb >= ROWS) rb = bn;
      stage16(bankB + (size_t)rb * CH + k0 + kk, Bs + u * 8);
    }
    __syncthreads();

    bf16x8 af[4], bf[4];
#pragma unroll
    for (int t4 = 0; t4 < 4; t4++) {
      af[t4] = *(const bf16x8*)(As + (wm + t4 * 16 + m_in) * 32 + ks);
      bf[t4] = *(const bf16x8*)(Bs + (wn + t4 * 16 + m_in) * 32 + ks);
    }
    // swapped operands: D[n][m] so regs q span 4 consecutive N columns
#pragma unroll
    for (int mi = 0; mi < 4; mi++)
#pragma unroll
      for (int ni = 0; ni < 4; ni++)
        acc[mi][ni] = __builtin_amdgcn_mfma_f32_16x16x32_bf16(bf[ni], af[mi], acc[mi][ni], 0, 0, 0);
  }

  const int cc = lane & 15;        // M offset within 16
  const int rr = (lane >> 4) * 4;  // N offset within 16
#pragma unroll
  for (int mi = 0; mi < 4; mi++) {
    const int row = bm + wm + mi * 16 + cc;  // always < 512
#pragma unroll
    for (int ni = 0; ni < 4; ni++) {
      const int n0 = bn + wn + ni * 16 + rr;
      if (n0 < ROWS) {  // n0 % 4 == 0 and ROWS % 4 == 0 -> whole group in/out
        u64 pk = (u64)f2b(acc[mi][ni][0]) | ((u64)f2b(acc[mi][ni][1]) << 16) |
                 ((u64)f2b(acc[mi][ni][2]) << 32) | ((u64)f2b(acc[mi][ni][3]) << 48);
        *(u64*)(Cb + (size_t)row * ROWS + n0) = pk;
      }
    }
  }
}

// ---------------- block helpers (1024 threads, wave=64) ----------------
__device__ __forceinline__ u32 wscan_incl(u32 v) {
  int lane = (int)(threadIdx.x & 63);
#pragma unroll
  for (int off = 1; off < 64; off <<= 1) {
    u32 t = __shfl_up(v, off, 64);
    if (lane >= off) v += t;
  }
  return v;
}

__device__ __forceinline__ u32 scan1024(u32 v, u32* tmp, int tid) {
  u32 inc = wscan_incl(v);
  int wid = tid >> 6;
  if ((tid & 63) == 63) tmp[wid] = inc;
  __syncthreads();
  if (tid < 64) {
    u32 t = (tid < 16) ? tmp[tid] : 0u;
    u32 ti = wscan_incl(t);
    if (tid < 16) tmp[tid] = ti - t;
  }
  __syncthreads();
  u32 r = inc + tmp[wid];
  __syncthreads();
  return r;
}

__device__ __forceinline__ float redsum1024(float v, float* tmp, int tid) {
#pragma unroll
  for (int off = 32; off > 0; off >>= 1) v += __shfl_xor(v, off, 64);
  int wid = tid >> 6;
  if ((tid & 63) == 0) tmp[wid] = v;
  __syncthreads();
  if (tid == 0) {
    float t = 0.f;
#pragma unroll
    for (int i = 0; i < 16; i++) t += tmp[i];
    tmp[0] = t;
  }
  __syncthreads();
  float r = tmp[0];
  __syncthreads();
  return r;
}

__device__ __forceinline__ int binof(float v, float lo, float scale) {
  int b = (int)((v - lo) * scale);
  return b < 0 ? 0 : (b > 2047 ? 2047 : b);
}

// ---------------- K4: per-row selection + loss terms ----------------
// FAST phase A: stream crow+rrow once; c-side = one NO-RETURN LDS atomicAdd
// into a 512-bin EXACT-bf16-VALUE histogram per passing element (bit-compare,
// no b2f, no slot reservation, no list); r-side = small (rv,mi) list.
// S_H computed exactly from the histogram (validated bit-exact r11/r12:
// boundary-bin values are identical -> addH = need_c*exp(v_b)).
// Phase B: only the r-list (c gathered from the just-streamed L2-hot crow).
// LEGACY full scan retry kept verbatim (rolled loops -- spill lesson r2-r4).
#define VITER 5
#define VTAIL 80
#define VTAILBASE 40960

__global__ __launch_bounds__(1024, 8) void k_select(const u16* __restrict__ Cb,
                                                    const float* __restrict__ rnd,
                                                    const int* __restrict__ label,
                                                    float* __restrict__ partial) {
  const int n = blockIdx.x;
  const int tid = threadIdx.x;
  const u16* crow = Cb + (size_t)n * ROWS;
  const float* rrow = rnd + (size_t)n * ROWS;
  const int lab = label[n];

  __shared__ __align__(16) char smem[56448];
  u32* histc = (u32*)(smem);                // 2048 u32 (fast: 512 exact bins; legacy: 2048 float bins; reused by positives)
  u32* histr = (u32*)(smem + 8192);         // 2048 u32
  float* clist = (float*)(smem + 16384);    // 3072 f32 (legacy only)
  float* rl_rv = (float*)(smem + 28672);    // 1536 f32
  float* rl_cv = (float*)(smem + 34816);    // 1536 f32 (legacy only)
  u32* rl_mi = (u32*)(smem + 40960);        // 1536 u32
  u32* stmp = (u32*)(smem + 47104);         // 1024 u32 (fred aliases)
  float* fred = (float*)(smem + 47104);
  float* cb_c = (float*)(smem + 51200);     // 512 f32
  float* rb_r = (float*)(smem + 53248);     // 256 f32
  float* rb_c = (float*)(smem + 54272);     // 256 f32
  u32* rb_m = (u32*)(smem + 55296);         // 256 u32
  u32* ctl = (u32*)(smem + 56320);
  float* bc_f = (float*)(ctl + 8);

  const int rv0 = (tid * 8) % 60;

  // ---- FAST phase A ----
  for (int i = tid; i < 2048; i += 1024) { histc[i] = 0; histr[i] = 0; }
  if (tid < 8) ctl[tid] = 0;
  __syncthreads();
  const float sc_r = 2048.0f / T0BASE;
  {
    int rb = rv0;
#pragma unroll 1
    for (int it = 0; it < VITER; it++) {
      int m8 = (it * 1024 + tid) * 8;
      uint4 cr = *(const uint4*)(crow + m8);
      float4 ra = *(const float4*)(rrow + m8);
      float4 rb4 = *(const float4*)(rrow + m8 + 4);
      u32 cw[4] = {cr.x, cr.y, cr.z, cr.w};
      float rs[8] = {ra.x, ra.y, ra.z, ra.w, rb4.x, rb4.y, rb4.z, rb4.w};
      u32 mr = 0;
      int r = rb;
#pragma unroll
      for (int j = 0; j < 8; j++) {
        u16 hb = (u16)(cw[j >> 1] >> ((j & 1) * 16));
        bool isneg = (r != lab);
        if (isneg && hb > 0x3DC0u && hb < 0x8000u) {
          u32 bin = (u32)hb - BASEC;
          if (bin < NBINC) atomicAdd(&histc[bin], 1u);  // no-return LDS atomic
          else ctl[2] = 1u;  // impossible for |c|<=1.06; safety -> legacy
        }
        if (isneg && rs[j] < T0BASE) mr |= (1u << j);
        r++;
        if (r == 60) r = 0;
      }
      u32 s2 = 0;
      if (mr) s2 = atomicAdd(&ctl[1], (u32)__popc(mr));
#pragma unroll
      for (int j = 0; j < 8; j++) {
        if (mr & (1u << j)) {
          if (s2 < CAPR) { rl_rv[s2] = rs[j]; rl_mi[s2] = (u32)(m8 + j); }
          atomicAdd(&histr[binof(rs[j], 0.0f, sc_r)], 1u);
          s2++;
        }
      }
      rb += 32;  // 8192 % 60
      if (rb >= 60) rb -= 60;
    }
    if (tid < VTAIL) {
      int m = VTAILBASE + tid;
      int r = 40 + tid;  // 40960 % 60 = 40
      if (r >= 60) r -= 60;
      bool isneg = (r != lab);
      u16 hb = crow[m];
      if (isneg && hb > 0x3DC0u && hb < 0x8000u) {
        u32 bin = (u32)hb - BASEC;
        if (bin < NBINC) atomicAdd(&histc[bin], 1u);
        else ctl[2] = 1u;
      }
      float rv = rrow[m];
      if (isneg && rv < T0BASE) {
        u32 s2 = atomicAdd(&ctl[1], 1u);
        if (s2 < CAPR) { rl_rv[s2] = rv; rl_mi[s2] = (u32)m; }
        atomicAdd(&histr[binof(rv, 0.0f, sc_r)], 1u);
      }
    }
  }
  __syncthreads();
  // F from exact-value histogram scan
  u32 cbc = (tid < NBINC) ? histc[tid] : 0u;
  u32 cinc = scan1024(cbc, stmp, tid);
  u32 cexc = cinc - cbc;
  if (tid == 1023) ctl[0] = cinc;
  __syncthreads();
  const u32 F = ctl[0];
  const u32 G = ctl[1];
  const u32 ovl = ctl[2];
  const bool fast = (ovl == 0u) && F >= NEGN && G >= NEGN && G <= CAPR;

  float S_H, S_R;
  if (fast) {
    if (tid == 0) { ctl[3] = 0; ctl[4] = 0; ctl[5] = 0; ctl[6] = 0; ctl[7] = 0; }
    __syncthreads();
    // c boundary from exact-value bins
    u32 tcpos = F - NEGN + 1;
    if (tid < NBINC && cexc < tcpos && tcpos <= cinc) {
      ctl[4] = (u32)tid;   // boundary bin
      ctl[5] = F - cinc;   // count strictly above boundary bin
    }
    __syncthreads();
    const u32 b_c = ctl[4], cnt_gt = ctl[5];
    const u32 need_c = NEGN - cnt_gt;
    float sH = 0.f;
    if (tid < NBINC && (u32)tid > b_c && cbc)
      sH = (float)cbc * expf(b2f((u16)(BASEC + (u32)tid)));
    float SHsum = redsum1024(sH, fred, tid);
    S_H = SHsum + (float)need_c * expf(b2f((u16)(BASEC + b_c)));

    // r boundary from histr
    u32 gsum = histr[tid * 2] + histr[tid * 2 + 1];
    u32 ginc = scan1024(gsum, stmp, tid);
    u32 gexc = ginc - gsum;
    if (gexc < NEGN && NEGN <= ginc) {
      u32 run = gexc;
#pragma unroll
      for (int i = 0; i < 2; i++) {
        u32 h = histr[tid * 2 + i];
        if (run + h >= NEGN) { ctl[6] = (u32)(tid * 2 + i); ctl[7] = run; break; }
        run += h;
      }
    }
    __syncthreads();
    const u32 b_r = ctl[6], cnt_lt = ctl[7];
    const u32 need_r = NEGN - cnt_lt;

    // phase B-r: gather c from crow (L2/L3-hot: streamed moments ago)
    float sR = 0.f;
    for (u32 i = tid; i < G; i += 1024) {
      float rv = rl_rv[i];
      u32 b = (u32)binof(rv, 0.0f, sc_r);
      if (b < b_r) sR += expf(b2f(crow[rl_mi[i]]));
      else if (b == b_r) {
        u32 id = atomicAdd(&ctl[3], 1u);
        if (id < 256) {
          rb_r[id] = rv;
          rb_c[id] = b2f(crow[rl_mi[i]]);
          rb_m[id] = rl_mi[i];
        }
      }
    }
    __syncthreads();
    float SRsum = redsum1024(sR, fred, tid);
    if (tid == 0) {
      // boundary bin: stable order = (rand value, index) ascending
      u32 Lr = umin2(ctl[3], 256u);
      for (u32 i = 1; i < Lr; i++) {
        float rv = rb_r[i]; u32 mm = rb_m[i]; float cv = rb_c[i];
        int j = (int)i - 1;
        while (j >= 0 && (rb_r[j] > rv || (rb_r[j] == rv && rb_m[j] > mm))) {
          rb_r[j + 1] = rb_r[j]; rb_m[j + 1] = rb_m[j]; rb_c[j + 1] = rb_c[j];
          j--;
        }
        rb_r[j + 1] = rv; rb_m[j + 1] = mm; rb_c[j + 1] = cv;
      }
      float addR = 0.f;
      u32 kr = umin2(need_r, Lr);
      for (u32 i = 0; i < kr; i++) addR += expf(rb_c[i]);
      bc_f[1] = addR;
    }
    __syncthreads();
    S_R = SRsum + bc_f[1];
    __syncthreads();
  } else {
    // ---- LEGACY: r5 full scan with retry (rolled loops; spill lesson r2-r4) ----
    float T1 = T1BASE, T0 = T0BASE;
    u32 Fl = 0, Gl = 0;
    float sc_c, sc_rl;
    for (int attempt = 0;; attempt++) {
      for (int i = tid; i < 2048; i += 1024) { histc[i] = 0; histr[i] = 0; }
      if (tid == 0) { ctl[0] = 0; ctl[1] = 0; }
      __syncthreads();
      sc_c = 2048.0f / (1.0625f - T1);
      sc_rl = 2048.0f / T0;
      int rb = rv0;
#pragma unroll 1
      for (int it = 0; it < VITER; it++) {
        int m8 = (it * 1024 + tid) * 8;
        uint4 cr = *(const uint4*)(crow + m8);
        float4 ra = *(const float4*)(rrow + m8);
        float4 rb4 = *(const float4*)(rrow + m8 + 4);
        u32 cw[4] = {cr.x, cr.y, cr.z, cr.w};
        float rs[8] = {ra.x, ra.y, ra.z, ra.w, rb4.x, rb4.y, rb4.z, rb4.w};
        u32 mc = 0, mr = 0;
        int r = rb;
#pragma unroll
        for (int j = 0; j < 8; j++) {
          bool isneg = (r != lab);
          float c = b2f((u16)(cw[j >> 1] >> ((j & 1) * 16)));
          if (isneg && c > T1) mc |= (1u << j);
          if (isneg && rs[j] < T0) mr |= (1u << j);
          r++;
          if (r == 60) r = 0;
        }
        u32 s1 = 0, s2 = 0;
        if (mc) s1 = atomicAdd(&ctl[0], (u32)__popc(mc));
        if (mr) s2 = atomicAdd(&ctl[1], (u32)__popc(mr));
#pragma unroll
        for (int j = 0; j < 8; j++) {
          if (mc & (1u << j)) {
            float c = b2f((u16)(cw[j >> 1] >> ((j & 1) * 16)));
            if (s1 < CAPC) clist[s1] = c;
            atomicAdd(&histc[binof(c, T1, sc_c)], 1u);
            s1++;
          }
          if (mr & (1u << j)) {
            float c = b2f((u16)(cw[j >> 1] >> ((j & 1) * 16)));
            if (s2 < CAPR) { rl_rv[s2] = rs[j]; rl_cv[s2] = c; rl_mi[s2] = (u32)(m8 + j); }
            atomicAdd(&histr[binof(rs[j], 0.0f, sc_rl)], 1u);
            s2++;
          }
        }
        rb += 32;
        if (rb >= 60) rb -= 60;
      }
      if (tid < VTAIL) {
        int m = VTAILBASE + tid;
        int r = 40 + tid;
        if (r >= 60) r -= 60;
        bool isneg = (r != lab);
        float c = b2f(crow[m]);
        if (isneg && c > T1) {
          u32 s1 = atomicAdd(&ctl[0], 1u);
          if (s1 < CAPC) clist[s1] = c;
          atomicAdd(&histc[binof(c, T1, sc_c)], 1u);
        }
        float rv = rrow[m];
        if (isneg && rv < T0) {
          u32 s2 = atomicAdd(&ctl[1], 1u);
          if (s2 < CAPR) { rl_rv[s2] = rv; rl_cv[s2] = c; rl_mi[s2] = (u32)m; }
          atomicAdd(&histr[binof(rv, 0.0f, sc_rl)], 1u);
        }
      }
      __syncthreads();
      Fl = ctl[0];
      Gl = ctl[1];
      __syncthreads();
      if (Fl >= NEGN && Gl >= NEGN) break;
      if (Fl < NEGN) T1 = -1.1f;
      if (Gl < NEGN) T0 = 1.1f;
    }
    const bool listc_ok = (Fl <= CAPC);
    const bool listr_ok = (Gl <= CAPR);

    if (tid == 0) { ctl[2] = 0; ctl[3] = 0; ctl[4] = 0; ctl[5] = 0; ctl[6] = 0; ctl[7] = 0; }
    u32 fsum = histc[tid * 2] + histc[tid * 2 + 1];
    u32 finc = scan1024(fsum, stmp, tid);
    u32 fexc = finc - fsum;
    u32 tcpos = Fl - NEGN + 1;
    if (fexc < tcpos && tcpos <= finc) {
      u32 run = fexc;
#pragma unroll
      for (int i = 0; i < 2; i++) {
        u32 h = histc[tid * 2 + i];
        if (run + h >= tcpos) { ctl[4] = (u32)(tid * 2 + i); ctl[5] = Fl - (run + h); break; }
        run += h;
      }
    }
    u32 gsum = histr[tid * 2] + histr[tid * 2 + 1];
    u32 ginc = scan1024(gsum, stmp, tid);
    u32 gexc = ginc - gsum;
    if (gexc < NEGN && NEGN <= ginc) {
      u32 run = gexc;
#pragma unroll
      for (int i = 0; i < 2; i++) {
        u32 h = histr[tid * 2 + i];
        if (run + h >= NEGN) { ctl[6] = (u32)(tid * 2 + i); ctl[7] = run; break; }
        run += h;
      }
    }
    __syncthreads();
    const u32 b_c = ctl[4], cnt_gt = ctl[5];
    const u32 b_r = ctl[6], cnt_lt = ctl[7];
    const u32 need_c = NEGN - cnt_gt;
    const u32 need_r = NEGN - cnt_lt;

    float sH = 0.f, sR = 0.f;
    if (listc_ok) {
      for (u32 i = tid; i < Fl; i += 1024) {
        float c = clist[i];
        u32 b = (u32)binof(c, T1, sc_c);
        if (b > b_c) sH += expf(c);
        else if (b == b_c) {
          u32 id = atomicAdd(&ctl[2], 1u);
          if (id < 512) cb_c[id] = c;
        }
      }
    }
    if (listr_ok) {
      for (u32 i = tid; i < Gl; i += 1024) {
        float rv = rl_rv[i];
        u32 b = (u32)binof(rv, 0.0f, sc_rl);
        if (b < b_r) sR += expf(rl_cv[i]);
        else if (b == b_r) {
          u32 id = atomicAdd(&ctl[3], 1u);
          if (id < 256) { rb_r[id] = rv; rb_c[id] = rl_cv[i]; rb_m[id] = rl_mi[i]; }
        }
      }
    }
    if (!listc_ok || !listr_ok) {
      for (int m = tid; m < ROWS; m += 1024) {
        int r = m % 60;
        if (r == lab) continue;
        float c = b2f(crow[m]);
        if (!listc_ok && c > T1) {
          u32 b = (u32)binof(c, T1, sc_c);
          if (b > b_c) sH += expf(c);
          else if (b == b_c) {
            u32 id = atomicAdd(&ctl[2], 1u);
            if (id < 512) cb_c[id] = c;
          }
        }
        if (!listr_ok) {
          float rv = rrow[m];
          if (rv < T0) {
            u32 b = (u32)binof(rv, 0.0f, sc_rl);
            if (b < b_r) sR += expf(c);
            else if (b == b_r) {
              u32 id = atomicAdd(&ctl[3], 1u);
              if (id < 256) { rb_r[id] = rv; rb_c[id] = c; rb_m[id] = (u32)m; }
            }
          }
        }
      }
    }
    __syncthreads();
    float SHsum = redsum1024(sH, fred, tid);
    float SRsum = redsum1024(sR, fred, tid);

    if (tid == 0) {
      float addH = 0.f;
      u32 Lc = umin2(ctl[2], 512u);
      u32 kc = umin2(need_c, Lc);
      for (u32 k = 0; k < kc; k++) {
        int best = 0;
        float bv = -3.0e38f;
        for (u32 i = 0; i < Lc; i++)
          if (cb_c[i] > bv) { bv = cb_c[i]; best = (int)i; }
        cb_c[best] = -3.0e38f;
        addH += expf(bv);
      }
      u32 Lr = umin2(ctl[3], 256u);
      for (u32 i = 1; i < Lr; i++) {
        float rv = rb_r[i]; u32 mm = rb_m[i]; float cv = rb_c[i];
        int j = (int)i - 1;
        while (j >= 0 && (rb_r[j] > rv || (rb_r[j] == rv && rb_m[j] > mm))) {
          rb_r[j + 1] = rb_r[j]; rb_m[j + 1] = rb_m[j]; rb_c[j + 1] = rb_c[j];
          j--;
        }
        rb_r[j + 1] = rv; rb_m[j + 1] = mm; rb_c[j + 1] = cv;
      }
      float addR = 0.f;
      u32 kr = umin2(need_r, Lr);
      for (u32 i = 0; i < kr; i++) addR += expf(rb_c[i]);
      bc_f[0] = addH;
      bc_f[1] = addR;
    }
    __syncthreads();
    S_H = SHsum + bc_f[0];
    S_R = SRsum + bc_f[1];
    __syncthreads();
  }

  // ---- positives: 128 smallest of 684 via histogram rank-selection ----
  float pval = 0.f;
  int pbin = 0;
  const bool hasp = tid < MEM;
  const float PLO = -1.03125f;
  const float PSC = 2048.0f / 2.09375f;
  if (hasp) {
    pval = b2f(crow[lab + CLS * tid]);
    pbin = binof(pval, PLO, PSC);
  }
  for (int i = tid; i < 2048; i += 1024) histc[i] = 0;
  if (tid == 0) { ctl[2] = 0; ctl[4] = 0; ctl[5] = 0; }
  __syncthreads();
  if (hasp) atomicAdd(&histc[pbin], 1u);
  __syncthreads();
  u32 hsum = histc[tid * 2] + histc[tid * 2 + 1];
  u32 hinc = scan1024(hsum, stmp, tid);
  u32 hexc = hinc - hsum;
  if (hexc < POSN && POSN <= hinc) {
    u32 run = hexc;
#pragma unroll
    for (int i = 0; i < 2; i++) {
      u32 h = histc[tid * 2 + i];
      if (run + h >= POSN) { ctl[4] = (u32)(tid * 2 + i); ctl[5] = run; break; }
      run += h;
    }
  }
  __syncthreads();
  const u32 b_p = ctl[4], cnt_below = ctl[5];
  const u32 need_p = POSN - cnt_below;
  if (hasp && (u32)pbin == b_p) {
    u32 id = atomicAdd(&ctl[2], 1u);
    if (id < 512) cb_c[id] = pval;
  }
  float term = 0.f;
  if (hasp && (u32)pbin < b_p) {
    float e = expf(pval);
    term = (pval - logf(e + S_H)) + (pval - logf(e + S_R));
  }
  __syncthreads();
  if (tid == 0) {
    u32 L = umin2(ctl[2], 512u);
    u32 kp = umin2(need_p, L);
    float add = 0.f;
    for (u32 k = 0; k < kp; k++) {
      int best = 0;
      float bv = 3.0e38f;
      for (u32 i = 0; i < L; i++)
        if (cb_c[i] < bv) { bv = cb_c[i]; best = (int)i; }
      cb_c[best] = 3.0e38f;
      float e = expf(bv);
      add += (bv - logf(e + S_H)) + (bv - logf(e + S_R));
    }
    bc_f[0] = add;
  }
  __syncthreads();
  float tot = redsum1024(term, fred, tid);
  if (tid == 0) partial[n] = tot + bc_f[0];
}

// ---------------- K5: final reduce ----------------
__global__ __launch_bounds__(256) void k_final(const float* __restrict__ partial,
                                               float* __restrict__ out) {
  __shared__ float fred[256];
  int tid = threadIdx.x;
  float v = partial[tid] + partial[tid + 256];
  fred[tid] = v;
  __syncthreads();
  for (int off = 128; off > 0; off >>= 1) {
    if (tid < off) fred[tid] += fred[tid + off];
    __syncthreads();
  }
  if (tid == 0) out[0] = -fred[0] / (float)(BATCHN * 2 * POSN);
}

extern "C" void kernel_launch(void* const* d_in, const int* in_sizes, int n_in,
                              void* d_out, int out_size, void* d_ws, size_t ws_size,
                              hipStream_t stream) {
  const float* f = (const float*)d_in[0];
  const int* label = (const int*)d_in[1];
  const int* enq = (const int*)d_in[2];
  const float* bank = (const float*)d_in[3];
  const float* rnd = (const float*)d_in[5];
  float* out = (float*)d_out;

  // workspace layout (~63.3 MB total)
  char* ws = (char*)d_ws;
  u16* bankB = (u16*)ws;                                     // 41040*256*2 = 21,012,480
  u16* fB = (u16*)(ws + 21012480);                           // 512*256*2   =    262,144
  u16* Cb = (u16*)(ws + 21012480 + 262144);                  // 512*41040*2 = 42,024,960
  float* partial = (float*)(ws + 21012480 + 262144 + 42024960);

  k_convert<<<dim3(5130), dim3(256), 0, stream>>>(bank, bankB);
  k_scatter<<<dim3(BATCHN), dim3(256), 0, stream>>>(f, enq, fB, bankB);
  k_gemm<<<dim3(1284), dim3(256), 0, stream>>>(fB, bankB, Cb);
  k_select<<<dim3(BATCHN), dim3(1024), 0, stream>>>(Cb, rnd, label, partial);
  k_final<<<dim3(1), dim3(256), 0, stream>>>(partial, out);
}